// Round 6
// baseline (330.626 us; speedup 1.0000x reference)
//
#include <hip/hip_runtime.h>
#include <math.h>

// Problem constants
#define NJ   24
#define JD   3
#define TS   120
#define B_TOT 16384
#define CT   (NJ * JD * TS)   // 8640 floats per batch row
#define CT4  (CT / 4)         // 2160 float4 per row
#define CT8  (CT / 8)         // 1080 8-float positions per row
#define NCHUNK 512            // batch chunks
#define BPC  (B_TOT / NCHUNK) // 32 batches per chunk

typedef float vfloat4 __attribute__((ext_vector_type(4)));

__global__ void pj_zero(float* __restrict__ sq) {
    int i = blockIdx.x * blockDim.x + threadIdx.x;
    if (i < CT) sq[i] = 0.0f;
}

// Each thread owns 8 contiguous float positions (two adjacent float4 slots) and
// strides over its batch chunk: 2 KiB contiguous per wave per stream per iter.
__global__ void pj_accum(const float* __restrict__ src,
                         const float* __restrict__ tgt,
                         float* __restrict__ sq) {
    int idx = blockIdx.x * blockDim.x + threadIdx.x;   // [0, CT8)
    if (idx >= CT8) return;
    const vfloat4* s = (const vfloat4*)src;
    const vfloat4* t = (const vfloat4*)tgt;
    long base = (long)blockIdx.y * BPC * CT4 + 2 * idx;
    float a0x=0.f,a0y=0.f,a0z=0.f,a0w=0.f, a1x=0.f,a1y=0.f,a1z=0.f,a1w=0.f;
    #pragma unroll 4
    for (int b = 0; b < BPC; ++b) {
        vfloat4 sa = __builtin_nontemporal_load(&s[base]);
        vfloat4 sb = __builtin_nontemporal_load(&s[base + 1]);
        vfloat4 ta = __builtin_nontemporal_load(&t[base]);
        vfloat4 tb = __builtin_nontemporal_load(&t[base + 1]);
        vfloat4 d0 = sa - ta;
        vfloat4 d1 = sb - tb;
        a0x += d0.x * d0.x; a0y += d0.y * d0.y; a0z += d0.z * d0.z; a0w += d0.w * d0.w;
        a1x += d1.x * d1.x; a1y += d1.y * d1.y; a1z += d1.z * d1.z; a1w += d1.w * d1.w;
        base += CT4;
    }
    float* q = &sq[idx * 8];
    atomicAdd(&q[0], a0x); atomicAdd(&q[1], a0y);
    atomicAdd(&q[2], a0z); atomicAdd(&q[3], a0w);
    atomicAdd(&q[4], a1x); atomicAdd(&q[5], a1y);
    atomicAdd(&q[6], a1z); atomicAdd(&q[7], a1w);
}

__global__ void pj_finalize(const float* __restrict__ sq, float* __restrict__ out) {
    float local = 0.0f;
    // 2880 (n,t) cells; each sums 3 joint-dim rows then sqrt
    for (int i = threadIdx.x; i < NJ * TS; i += blockDim.x) {
        int n = i / TS, t = i - (i / TS) * TS;
        float s = sq[(3 * n + 0) * TS + t]
                + sq[(3 * n + 1) * TS + t]
                + sq[(3 * n + 2) * TS + t];
        local += sqrtf(s);
    }
    // wave reduce (64 lanes)
    for (int off = 32; off > 0; off >>= 1)
        local += __shfl_down(local, off, 64);
    __shared__ float red[4];
    int lane = threadIdx.x & 63, wid = threadIdx.x >> 6;
    if (lane == 0) red[wid] = local;
    __syncthreads();
    if (threadIdx.x == 0) {
        float tot = 0.f;
        int nw = blockDim.x >> 6;
        for (int w = 0; w < nw; ++w) tot += red[w];
        out[0] = tot;
    }
}

extern "C" void kernel_launch(void* const* d_in, const int* in_sizes, int n_in,
                              void* d_out, int out_size, void* d_ws, size_t ws_size,
                              hipStream_t stream) {
    const float* src = (const float*)d_in[0];
    const float* tgt = (const float*)d_in[1];
    float* sq = (float*)d_ws;          // 8640 floats = 34.6 KB scratch
    float* out = (float*)d_out;

    pj_zero<<<(CT + 255) / 256, 256, 0, stream>>>(sq);

    dim3 grid((CT8 + 255) / 256, NCHUNK);   // (5, 512)
    pj_accum<<<grid, 256, 0, stream>>>(src, tgt, sq);

    pj_finalize<<<1, 256, 0, stream>>>(sq, out);
}

// Round 7
// 200.912 us; speedup vs baseline: 1.6456x; 1.6456x over previous
//
#include <hip/hip_runtime.h>
#include <math.h>

// Problem constants
#define NJ   24
#define JD   3
#define TS   120
#define B_TOT 16384
#define CT   (NJ * JD * TS)     // 8640 floats per batch row
#define CT4  (CT / 4)           // 2160 float4 per row
#define FL4_TOT ((long)B_TOT * CT4)  // 35,389,440 float4 total
#define NBLK 2160               // blocks; 2160*256 threads = 16 rows' worth of float4
#define THREADS (NBLK * 256)    // 552,960; THREADS % CT4 == 0 -> fixed per-thread position
#define ITERS ((int)(FL4_TOT / THREADS))  // 64, exact

typedef float vfloat4 __attribute__((ext_vector_type(4)));

__global__ void pj_zero(float* __restrict__ sq) {
    int i = blockIdx.x * blockDim.x + threadIdx.x;
    if (i < CT) sq[i] = 0.0f;
}

// Whole grid walks src/tgt as one contiguous sliding window (stride = THREADS
// float4 = 8.8 MB). THREADS is a multiple of CT4, so each thread's position
// within a row (p = tid mod CT4) is FIXED -> accumulate in registers, 4 atomics
// at the end. Per-instruction: lane i reads 16B at stride 16B -> perfect
// coalescing; cohort footprint is contiguous like the 6.6 TB/s fill kernels.
__global__ void pj_accum(const float* __restrict__ src,
                         const float* __restrict__ tgt,
                         float* __restrict__ sq) {
    int tid = blockIdx.x * 256 + threadIdx.x;
    int p = tid % CT4;              // fixed row-position of this thread
    const vfloat4* s = (const vfloat4*)src;
    const vfloat4* t = (const vfloat4*)tgt;
    long k = tid;
    float ax = 0.f, ay = 0.f, az = 0.f, aw = 0.f;
    #pragma unroll 8
    for (int j = 0; j < ITERS; ++j) {
        vfloat4 a = __builtin_nontemporal_load(&s[k]);
        vfloat4 c = __builtin_nontemporal_load(&t[k]);
        vfloat4 d = a - c;
        ax += d.x * d.x; ay += d.y * d.y; az += d.z * d.z; aw += d.w * d.w;
        k += THREADS;
    }
    atomicAdd(&sq[p * 4 + 0], ax);
    atomicAdd(&sq[p * 4 + 1], ay);
    atomicAdd(&sq[p * 4 + 2], az);
    atomicAdd(&sq[p * 4 + 3], aw);
}

__global__ void pj_finalize(const float* __restrict__ sq, float* __restrict__ out) {
    float local = 0.0f;
    // 2880 (n,t) cells; each sums 3 joint-dim rows then sqrt
    for (int i = threadIdx.x; i < NJ * TS; i += blockDim.x) {
        int n = i / TS, t = i - (i / TS) * TS;
        float s = sq[(3 * n + 0) * TS + t]
                + sq[(3 * n + 1) * TS + t]
                + sq[(3 * n + 2) * TS + t];
        local += sqrtf(s);
    }
    // wave reduce (64 lanes)
    for (int off = 32; off > 0; off >>= 1)
        local += __shfl_down(local, off, 64);
    __shared__ float red[4];
    int lane = threadIdx.x & 63, wid = threadIdx.x >> 6;
    if (lane == 0) red[wid] = local;
    __syncthreads();
    if (threadIdx.x == 0) {
        float tot = 0.f;
        int nw = blockDim.x >> 6;
        for (int w = 0; w < nw; ++w) tot += red[w];
        out[0] = tot;
    }
}

extern "C" void kernel_launch(void* const* d_in, const int* in_sizes, int n_in,
                              void* d_out, int out_size, void* d_ws, size_t ws_size,
                              hipStream_t stream) {
    const float* src = (const float*)d_in[0];
    const float* tgt = (const float*)d_in[1];
    float* sq = (float*)d_ws;          // 8640 floats = 34.6 KB scratch
    float* out = (float*)d_out;

    pj_zero<<<(CT + 255) / 256, 256, 0, stream>>>(sq);

    pj_accum<<<NBLK, 256, 0, stream>>>(src, tgt, sq);

    pj_finalize<<<1, 256, 0, stream>>>(sq, out);
}